// Round 11
// baseline (235.114 us; speedup 1.0000x reference)
//
#include <hip/hip_runtime.h>
#include <hip/hip_bf16.h>
#include <math.h>

#define NB 32768
#define DD 128
#define HH 512
#define EE 16
#define TM 64
#define GY 64

typedef __attribute__((ext_vector_type(8))) short short8;
typedef __attribute__((ext_vector_type(4))) float f32x4;
typedef __attribute__((ext_vector_type(16))) float f32x16;

__device__ __forceinline__ unsigned short f2bf(float f) {
  union { float f; unsigned u; } v; v.f = f;
  unsigned r = v.u + 0x7fffu + ((v.u >> 16) & 1u);
  return (unsigned short)(r >> 16);
}

// Abramowitz-Stegun 7.1.26 erf, |eps| <= 1.5e-7; v_rcp (1 ULP) instead of IEEE div
__device__ __forceinline__ float fast_erf(float z) {
  float a = fabsf(z);
  float t = __builtin_amdgcn_rcpf(1.0f + 0.3275911f * a);
  float y = t * (0.254829592f + t * (-0.284496736f + t * (1.421413741f +
            t * (-1.453152027f + t * 1.061405429f))));
  float r = 1.0f - y * __expf(-a * a);
  return z < 0.0f ? -r : r;
}

// ---------------- fused prep: gate (blocks 0..511) + weight repack (512..1023) ----------
// UNCHANGED from R8/R9 (harness-verified). Fragment-major wP: per expert 256 blocks of
// 1KB; block = one 64-lane x 16B wave-load = one MFMA operand fragment.
//   w1 fragment (hc,t,ks), elem (l,j) = w1[e][d = ks*16+(l>>5)*8+j][h = hc*64+t*32+(l&31)]
//   w2 fragment (hc,s,dt), elem (l,j) = w2[e][h'][dout = dt*32+(l&31)],
//     h' = hc*64 + (s>>1)*32 + (j&3) + 8*((s&1)+2*(j>>2)) + 4*(l>>5)   (sigma, bijective)
__global__ __launch_bounds__(256) void prep_kernel(
    const float* __restrict__ x, const float* __restrict__ wg,
    const float* __restrict__ bg, const float* __restrict__ w1,
    const float* __restrict__ w2, int* __restrict__ counts,
    int* __restrict__ rows, unsigned short* __restrict__ wP) {
  __shared__ __align__(16) char smem[50816];
  int tid = threadIdx.x;

  if (blockIdx.x >= 512) {
    int l = tid & 63, lc = l & 31, hi = l >> 5;
    int gw = (blockIdx.x - 512) * 4 + (tid >> 6);
    #pragma unroll
    for (int i = 0; i < 2; ++i) {
      int kb = gw * 2 + i;              // [0, 4096)
      int e = kb >> 8, v = kb & 255;
      float vals[8];
      if (v < 128) {
        int hc = v >> 4, t = (v >> 3) & 1, ks = v & 7;
        int h = hc * 64 + t * 32 + lc;
        const float* src = w1 + (size_t)e * DD * HH + h;
        int d0 = ks * 16 + hi * 8;
        #pragma unroll
        for (int j = 0; j < 8; ++j) vals[j] = src[(size_t)(d0 + j) * HH];
      } else {
        int b2 = v - 128;
        int hc = b2 >> 4, s = (b2 >> 2) & 3, dt = b2 & 3;
        int dout = dt * 32 + lc;
        const float* src = w2 + (size_t)e * HH * DD + dout;
        #pragma unroll
        for (int j = 0; j < 8; ++j) {
          int hp = hc * 64 + (s >> 1) * 32 + (j & 3) + 8 * ((s & 1) + 2 * (j >> 2)) + 4 * hi;
          vals[j] = src[(size_t)hp * DD];
        }
      }
      ushort4 p0, p1;
      p0.x = f2bf(vals[0]); p0.y = f2bf(vals[1]); p0.z = f2bf(vals[2]); p0.w = f2bf(vals[3]);
      p1.x = f2bf(vals[4]); p1.y = f2bf(vals[5]); p1.z = f2bf(vals[6]); p1.w = f2bf(vals[7]);
      unsigned short* dst = wP + (size_t)kb * 512 + l * 8;
      *(ushort4*)dst = p0;
      *(ushort4*)(dst + 4) = p1;
    }
    return;
  }

  // ---- gating: fp64 logits + block-aggregated bucket scatter (unchanged) ----
  float  (*sx)[132] = (float (*)[132])smem;
  double (*swg)[EE] = (double (*)[EE])(smem + 33792);
  int* lcnt  = (int*)(smem + 50176);
  int* gbase = lcnt + EE;
  int* lslot = gbase + EE;
  int* lexp  = lslot + 64;

  int base = blockIdx.x * 64;
  if (tid < EE) lcnt[tid] = 0;
  for (int i = tid; i < DD * EE; i += 256) swg[i >> 4][i & 15] = (double)wg[i];
  {
    int r = tid >> 2, c0 = (tid & 3) * 32;
    const float4* src = (const float4*)(x + (size_t)(base + r) * DD + c0);
    #pragma unroll
    for (int i = 0; i < 8; ++i)
      *(float4*)&sx[r][c0 + i * 4] = src[i];
  }
  __syncthreads();

  int r = tid >> 2;
  int e0 = (tid & 3) * 4;
  double acc[4];
  #pragma unroll
  for (int j = 0; j < 4; ++j) acc[j] = (double)bg[e0 + j];

  #pragma unroll 4
  for (int d = 0; d < DD; ++d) {
    double xv = (double)sx[r][d];
    #pragma unroll
    for (int j = 0; j < 4; ++j)
      acc[j] += xv * swg[d][e0 + j];
  }

  int beste = 0; double bestv = acc[0];
  #pragma unroll
  for (int j = 1; j < 4; ++j)
    if (acc[j] > bestv) { bestv = acc[j]; beste = j; }
  int ge = e0 + beste;

  #pragma unroll
  for (int off = 1; off < 4; off <<= 1) {
    double ov = __shfl_xor(bestv, off);
    int oe = __shfl_xor(ge, off);
    if (ov > bestv || (ov == bestv && oe < ge)) { bestv = ov; ge = oe; }
  }

  if ((tid & 3) == 0) {
    lslot[r] = atomicAdd(&lcnt[ge], 1);
    lexp[r] = ge;
  }
  __syncthreads();
  if (tid < EE && lcnt[tid] > 0)
    gbase[tid] = atomicAdd(&counts[tid], lcnt[tid]);
  __syncthreads();
  if ((tid & 3) == 0) {
    int e2 = lexp[r];
    rows[e2 * NB + gbase[e2] + lslot[r]] = base + r;
  }
}

// ---------------- grouped expert GEMM: out[r] = gelu(x[r]@w1[e]) @ w2[e] ----------------
// v12 (resubmitted unchanged after R10 infra failure): H-HALF waves + deep register
//   prefetch. Block = 4 waves = (row-tile rt) x (H-half hh); wave computes its 32 rows
//   over hc = hh*4..hh*4+3 (straight-line, no LDS, no barriers in the hot loop), one 32KB
//   LDS combine per tile. 2048 real waves = 2/SIMD, and at __launch_bounds__(256,2) the
//   per-wave register budget is 256: live set ~120 leaves >100 regs of slack so the
//   compiler can keep MANY weight fragments in flight (v10's 84-VGPR fit allowed ~2 ->
//   ~500cy exposed latency per step; that was the 43-56us floor across R2-R8).
//   Persistent tile-stride loop (ty += GY) kills R8/R9's 7680 empty blocks; worst-case
//   routing still correct (barriers are uniform: trip count depends only on cnt).
//   Linear block id = e + 16*ty -> id%8 = e%8: each XCD serves 2 experts, 512KB weights,
//   L2-resident.
//   Mappings identical to verified v10/v11 (32x32 D: col=lane&31, row=(r&3)+8*(r>>2)+4*hi):
//     GEMM1 D: a1[r] = H[m=lc][h = hc*64+t*32+(r&3)+8*(r>>2)+4*hi]
//     GEMM2 A: hf8[j] = gelu(a1[(j&3)|(s2<<2)|((j>>2)<<3)]),  s = 2t+s2 (sigma-matched wP)
//     GEMM2 D: acc2[dt][reg] = C[m=(reg&3)+8*(reg>>2)+4*hi][dout = dt*32+lc]
__global__ __launch_bounds__(256, 2) void moe_gemm(
    const float* __restrict__ x, const unsigned short* __restrict__ wP,
    const int* __restrict__ counts, const int* __restrict__ rows,
    float* __restrict__ out) {
  int e = blockIdx.x;
  int cnt = counts[e];

  __shared__ float sc[8192];          // 32 KB combine scratch: [rt][dt*16+r][l]

  int tid = threadIdx.x;
  int wv = tid >> 6, l = tid & 63;
  int lc = l & 31, hi = l >> 5;
  int rt = wv & 1;                    // row-tile within the 64-row block tile
  int hh = wv >> 1;                   // H-half: hc in [hh*4, hh*4+4)

  const unsigned short* we = wP + (size_t)e * 256 * 512;

  for (int ty = blockIdx.y; ty * TM < cnt; ty += GY) {
    int mb = ty * TM + rt * 32;       // this wave's 32-row tile

    // X as GEMM1 B-operand: xa[ks] elem j = X[m=lc][d = ks*16 + hi*8 + j]
    short8 xa[8];
    {
      int ridx = mb + lc; if (ridx >= cnt) ridx = cnt - 1;
      int grow = rows[e * NB + ridx];
      const float* xr = x + (size_t)grow * DD + hi * 8;
      #pragma unroll
      for (int ks = 0; ks < 8; ++ks) {
        f32x4 v0 = *(const f32x4*)(xr + ks * 16);
        f32x4 v1 = *(const f32x4*)(xr + ks * 16 + 4);
        short8 a;
        a[0] = f2bf(v0[0]); a[1] = f2bf(v0[1]); a[2] = f2bf(v0[2]); a[3] = f2bf(v0[3]);
        a[4] = f2bf(v1[0]); a[5] = f2bf(v1[1]); a[6] = f2bf(v1[2]); a[7] = f2bf(v1[3]);
        xa[ks] = a;
      }
    }

    f32x16 acc2[4];
    #pragma unroll
    for (int dt = 0; dt < 4; ++dt)
      #pragma unroll
      for (int r = 0; r < 16; ++r) acc2[dt][r] = 0.f;

    // ---- main loop: this wave's H-half (4 hc-blocks), straight-line, no barriers ----
    #pragma unroll
    for (int hcL = 0; hcL < 4; ++hcL) {
      int hc = hh * 4 + hcL;
      const unsigned short* wc1 = we + (size_t)hc * 16 * 512 + l * 8;           // w1 frags
      const unsigned short* wc2 = we + (size_t)(128 + hc * 16) * 512 + l * 8;   // w2 frags
      #pragma unroll
      for (int t = 0; t < 2; ++t) {
        f32x16 a1;
        #pragma unroll
        for (int r = 0; r < 16; ++r) a1[r] = 0.f;
        #pragma unroll
        for (int ks = 0; ks < 8; ++ks) {
          short8 wf = *(const short8*)(wc1 + (t * 8 + ks) * 512);
          a1 = __builtin_amdgcn_mfma_f32_32x32x16_bf16(wf, xa[ks], a1, 0, 0, 0);
        }
        #pragma unroll
        for (int s2 = 0; s2 < 2; ++s2) {
          short8 hf8;
          #pragma unroll
          for (int j = 0; j < 8; ++j) {
            int r = (j & 3) | (s2 << 2) | ((j >> 2) << 3);
            float v = a1[r];
            float g = 0.5f * v * (1.0f + fast_erf(v * 0.70710678118654752f));
            hf8[j] = (short)f2bf(g);
          }
          int s = 2 * t + s2;
          #pragma unroll
          for (int dt = 0; dt < 4; ++dt) {
            short8 wf = *(const short8*)(wc2 + (s * 4 + dt) * 512);
            acc2[dt] = __builtin_amdgcn_mfma_f32_32x32x16_bf16(hf8, wf, acc2[dt], 0, 0, 0);
          }
        }
      }
    }

    // ---- combine the two H-half partials; (dt*16+r)*64+l is 2-way (free) ----
    if (hh == 1) {
      float* d = sc + rt * 4096;
      #pragma unroll
      for (int dt = 0; dt < 4; ++dt)
        #pragma unroll
        for (int r = 0; r < 16; ++r) d[(dt * 16 + r) * 64 + l] = acc2[dt][r];
    }
    __syncthreads();
    if (hh == 0) {
      const float* s = sc + rt * 4096;
      #pragma unroll
      for (int reg = 0; reg < 16; ++reg) {
        int m = (reg & 3) + 8 * (reg >> 2) + 4 * hi;
        int ridx = mb + m;
        if (ridx < cnt) {
          int grow = rows[e * NB + ridx];
          float* op = out + (size_t)grow * DD + lc;
          op[0]  = acc2[0][reg] + s[(0 * 16 + reg) * 64 + l];
          op[32] = acc2[1][reg] + s[(1 * 16 + reg) * 64 + l];
          op[64] = acc2[2][reg] + s[(2 * 16 + reg) * 64 + l];
          op[96] = acc2[3][reg] + s[(3 * 16 + reg) * 64 + l];
        }
      }
    }
    __syncthreads();   // sc reusable next tile
  }
}

extern "C" void kernel_launch(void* const* d_in, const int* in_sizes, int n_in,
                              void* d_out, int out_size, void* d_ws, size_t ws_size,
                              hipStream_t stream) {
  const float* x  = (const float*)d_in[0];
  const float* w1 = (const float*)d_in[1];
  const float* w2 = (const float*)d_in[2];
  const float* wg = (const float*)d_in[3];
  const float* bg = (const float*)d_in[4];
  float* out = (float*)d_out;

  // workspace: [0,64) counts ; [1024, +2MB) rows ; wP bf16 4MB (fragment-major)
  int* counts = (int*)d_ws;
  int* rows   = (int*)((char*)d_ws + 1024);
  unsigned short* wP = (unsigned short*)((char*)d_ws + 1024 + (size_t)EE * NB * 4);

  hipMemsetAsync(d_ws, 0, 64, stream);
  hipLaunchKernelGGL(prep_kernel, dim3(1024), dim3(256), 0, stream,
                     x, wg, bg, w1, w2, counts, rows, wP);
  hipLaunchKernelGGL(moe_gemm, dim3(EE, GY), dim3(256), 0, stream,
                     x, wP, counts, rows, out);
}

// Round 12
// 128.968 us; speedup vs baseline: 1.8230x; 1.8230x over previous
//
#include <hip/hip_runtime.h>
#include <hip/hip_bf16.h>
#include <math.h>

#define NB 32768
#define DD 128
#define HH 512
#define EE 16
#define TM 64
#define HC 64
#define NCH (HH / HC)

typedef __attribute__((ext_vector_type(8))) short short8;
typedef __attribute__((ext_vector_type(4))) float f32x4;
typedef __attribute__((address_space(1))) const unsigned short gc_us;
typedef __attribute__((address_space(3))) unsigned short lds_us;

__device__ __forceinline__ unsigned short f2bf(float f) {
  union { float f; unsigned u; } v; v.f = f;
  unsigned r = v.u + 0x7fffu + ((v.u >> 16) & 1u);
  return (unsigned short)(r >> 16);
}

// Abramowitz-Stegun 7.1.26 erf, |eps| <= 1.5e-7; v_rcp (1 ULP) instead of IEEE div
__device__ __forceinline__ float fast_erf(float z) {
  float a = fabsf(z);
  float t = __builtin_amdgcn_rcpf(1.0f + 0.3275911f * a);
  float y = t * (0.254829592f + t * (-0.284496736f + t * (1.421413741f +
            t * (-1.453152027f + t * 1.061405429f))));
  float r = 1.0f - y * __expf(-a * a);
  return z < 0.0f ? -r : r;
}

// ---------------- fused prep: gate (blocks 0..511) + weight transpose (512..1023) ----------
// UNCHANGED from R7 (harness-verified). w2T gets the sigma h-permutation baked in:
// w2T[e][d][K] = w2[e][hsig(K)][d], hsig(K) = (K&~31)|((K&4)<<2)|((K&24)>>1)|(K&3).
__global__ __launch_bounds__(256) void prep_kernel(
    const float* __restrict__ x, const float* __restrict__ wg,
    const float* __restrict__ bg, const float* __restrict__ w1,
    const float* __restrict__ w2, int* __restrict__ counts,
    int* __restrict__ rows, unsigned short* __restrict__ w1T,
    unsigned short* __restrict__ w2T) {
  __shared__ __align__(16) char smem[50816];
  int tid = threadIdx.x;

  if (blockIdx.x >= 512) {
    float (*tile)[65] = (float (*)[65])smem;
    int tp = blockIdx.x - 512;
    const float* src; unsigned short* dst; int S, Sd; int isw2;
    if (tp < 256) {
      int e = tp >> 4, t2 = tp & 15;
      int d0 = (t2 >> 3) * 64, h0 = (t2 & 7) * 64;
      src = w1 + (size_t)e * DD * HH + (size_t)d0 * HH + h0; S = HH;
      dst = w1T + (size_t)e * HH * DD + (size_t)h0 * DD + d0; Sd = DD;
      isw2 = 0;
    } else {
      int t = tp - 256;
      int e = t >> 4, t2 = t & 15;
      int h0 = (t2 >> 1) * 64, d0 = (t2 & 1) * 64;
      src = w2 + (size_t)e * HH * DD + (size_t)h0 * DD + d0; S = DD;
      dst = w2T + (size_t)e * DD * HH + (size_t)d0 * HH + h0; Sd = HH;
      isw2 = 1;
    }
    #pragma unroll
    for (int i = 0; i < 4; ++i) {
      int u = tid + i * 256, r = u >> 4, c = (u & 15) * 4;
      int rs = isw2 ? ((r & 32) | ((r & 4) << 2) | ((r & 24) >> 1) | (r & 3)) : r;
      float4 v = *(const float4*)(src + (size_t)rs * S + c);
      tile[r][c + 0] = v.x; tile[r][c + 1] = v.y;
      tile[r][c + 2] = v.z; tile[r][c + 3] = v.w;
    }
    __syncthreads();
    #pragma unroll
    for (int i = 0; i < 4; ++i) {
      int u = tid + i * 256, tr = u >> 4, tc = (u & 15) * 4;
      ushort4 p;
      p.x = f2bf(tile[tc + 0][tr]); p.y = f2bf(tile[tc + 1][tr]);
      p.z = f2bf(tile[tc + 2][tr]); p.w = f2bf(tile[tc + 3][tr]);
      *(ushort4*)(dst + (size_t)tr * Sd + tc) = p;
    }
    return;
  }

  // ---- gating: fp64 logits + block-aggregated bucket scatter ----
  float  (*sx)[132] = (float (*)[132])smem;
  double (*swg)[EE] = (double (*)[EE])(smem + 33792);
  int* lcnt  = (int*)(smem + 50176);
  int* gbase = lcnt + EE;
  int* lslot = gbase + EE;
  int* lexp  = lslot + 64;

  int base = blockIdx.x * 64;
  if (tid < EE) lcnt[tid] = 0;
  for (int i = tid; i < DD * EE; i += 256) swg[i >> 4][i & 15] = (double)wg[i];
  {
    int r = tid >> 2, c0 = (tid & 3) * 32;
    const float4* src = (const float4*)(x + (size_t)(base + r) * DD + c0);
    #pragma unroll
    for (int i = 0; i < 8; ++i)
      *(float4*)&sx[r][c0 + i * 4] = src[i];
  }
  __syncthreads();

  int r = tid >> 2;
  int e0 = (tid & 3) * 4;
  double acc[4];
  #pragma unroll
  for (int j = 0; j < 4; ++j) acc[j] = (double)bg[e0 + j];

  #pragma unroll 4
  for (int d = 0; d < DD; ++d) {
    double xv = (double)sx[r][d];
    #pragma unroll
    for (int j = 0; j < 4; ++j)
      acc[j] += xv * swg[d][e0 + j];
  }

  int beste = 0; double bestv = acc[0];
  #pragma unroll
  for (int j = 1; j < 4; ++j)
    if (acc[j] > bestv) { bestv = acc[j]; beste = j; }
  int ge = e0 + beste;

  #pragma unroll
  for (int off = 1; off < 4; off <<= 1) {
    double ov = __shfl_xor(bestv, off);
    int oe = __shfl_xor(ge, off);
    if (ov > bestv || (ov == bestv && oe < ge)) { bestv = ov; ge = oe; }
  }

  if ((tid & 3) == 0) {
    lslot[r] = atomicAdd(&lcnt[ge], 1);
    lexp[r] = ge;
  }
  __syncthreads();
  if (tid < EE && lcnt[tid] > 0)
    gbase[tid] = atomicAdd(&counts[tid], lcnt[tid]);
  __syncthreads();
  if ((tid & 3) == 0) {
    int e2 = lexp[r];
    rows[e2 * NB + gbase[e2] + lslot[r]] = base + r;
  }
}

// ---------------- grouped expert GEMM: out[r] = gelu(x[r]@w1[e]) @ w2[e] ----------------
// v14 = R7's v9 (best measured: 43.2us) + NON-TEMPORAL hints on the read-once/write-once
//   streams (x gathers, rows lookups, out scatters). Theory: those streams evict the
//   16-expert weight set (4MB, XCD-pinned 512KB each via id%8) from the per-XCD L2, so
//   chunk DMAs refetch from L3/HBM at 600-900cy -- unhideable at 2-4 waves/SIMD. That is
//   the 43-56us floor of R2-R8 (FETCH 10.4MB = 2.5x the 4MB weight minimum). nt loads
//   don't allocate in L2 -> weights stay resident -> DMA becomes L2-hit.
//   Everything else byte-identical to verified v9 (sigma-w2T, swapped GEMM1, lane-local
//   gelu, dbuf DMA staging, one barrier/chunk).
__global__ __launch_bounds__(512, 4) void moe_gemm(
    const float* __restrict__ x, const unsigned short* __restrict__ w1T,
    const unsigned short* __restrict__ w2T, const int* __restrict__ counts,
    const int* __restrict__ rows, float* __restrict__ out) {
  int e = blockIdx.x;
  int cnt = counts[e];
  int base = blockIdx.y * TM;
  if (base >= cnt) return;

  // LDS: sW1[2][8192] | sW2[2][8192]  (65536 B, 2 blocks/CU)
  __shared__ __align__(16) unsigned short smem[32768];
  unsigned short* sW1 = smem;
  unsigned short* sW2 = smem + 16384;

  int tid = threadIdx.x;
  int wv = tid >> 6, l = tid & 63;
  int lm = l & 15, q = l >> 4;
  int rg = wv & 3;       // row group: rows [rg*16, rg*16+16)
  int hf = wv >> 2;      // H half:    h in [hf*32, hf*32+32) of each 64-chunk

  const unsigned short* w1e = w1T + (size_t)e * HH * DD;
  const unsigned short* w2e = w2T + (size_t)e * DD * HH;

  // X fragments in registers (nt: read-once stream, keep out of L2)
  short8 xa[4];
  {
    int ridx = base + rg * 16 + lm; if (ridx >= cnt) ridx = cnt - 1;
    int grow = __builtin_nontemporal_load(&rows[e * NB + ridx]);
    const float* xr = x + (size_t)grow * DD + q * 8;
    #pragma unroll
    for (int ks = 0; ks < 4; ++ks) {
      f32x4 v0 = __builtin_nontemporal_load((const f32x4*)(xr + ks * 32));
      f32x4 v1 = __builtin_nontemporal_load((const f32x4*)(xr + ks * 32 + 4));
      short8 a;
      a[0] = f2bf(v0[0]); a[1] = f2bf(v0[1]); a[2] = f2bf(v0[2]); a[3] = f2bf(v0[3]);
      a[4] = f2bf(v1[0]); a[5] = f2bf(v1[1]); a[6] = f2bf(v1[2]); a[7] = f2bf(v1[3]);
      xa[ks] = a;
    }
  }

  // direct-to-LDS staging: waves 0-3 own sW1 (4x 1KB DMA), waves 4-7 own sW2
  auto stage_chunk = [&](int buf, int c) {
    if (wv < 4) {
      const unsigned short* w1c = w1e + (size_t)c * HC * DD;
      #pragma unroll
      for (int i = 0; i < 4; ++i) {
        int r = wv * 16 + i * 4 + (l >> 4);
        const unsigned short* g = w1c + (size_t)r * DD + (((l & 15) ^ (r & 7)) << 3);
        __builtin_amdgcn_global_load_lds((gc_us*)g,
            (lds_us*)(sW1 + buf * 8192 + wv * 2048 + i * 512), 16, 0, 0);
      }
    } else {
      int wz = wv - 4;
      const unsigned short* w2c = w2e + (size_t)c * HC;
      #pragma unroll
      for (int i = 0; i < 4; ++i) {
        int r = wz * 32 + i * 8 + (l >> 3);
        const unsigned short* g = w2c + (size_t)r * HH + (((l & 7) ^ (r & 7)) << 3);
        __builtin_amdgcn_global_load_lds((gc_us*)g,
            (lds_us*)(sW2 + buf * 8192 + wz * 2048 + i * 512), 16, 0, 0);
      }
    }
  };

  stage_chunk(0, 0);
  __syncthreads();

  f32x4 acc2[8];
  #pragma unroll
  for (int n = 0; n < 8; ++n) acc2[n] = (f32x4){0.f, 0.f, 0.f, 0.f};

  for (int hc = 0; hc < NCH; ++hc) {
    int b = hc & 1;

    // next chunk's DMA flies under this chunk's compute
    if (hc + 1 < NCH) stage_chunk(b ^ 1, hc + 1);

    // GEMM1 (swapped): H^T(32h x 16m per wave) = W1chunk[hf-half] @ X^T
    f32x4 acc1[2];
    #pragma unroll
    for (int n = 0; n < 2; ++n) acc1[n] = (f32x4){0.f, 0.f, 0.f, 0.f};
    #pragma unroll
    for (int ks = 0; ks < 4; ++ks) {
      #pragma unroll
      for (int n = 0; n < 2; ++n) {
        int row = hf * 32 + n * 16 + lm;
        int sl = ((ks * 4 + q) ^ (row & 7)) * 8;
        short8 wfr = *(const short8*)&sW1[b * 8192 + row * DD + sl];
        acc1[n] = __builtin_amdgcn_mfma_f32_16x16x32_bf16(wfr, xa[ks], acc1[n], 0, 0, 0);
      }
    }
    // gelu + repack: fully lane-local (no LDS). ha[j] = gelu(acc1[j>>2][j&3])
    short8 ha;
    #pragma unroll
    for (int j = 0; j < 8; ++j) {
      float v = acc1[j >> 2][j & 3];
      float g = 0.5f * v * (1.0f + fast_erf(v * 0.70710678118654752f));
      ha[j] = (short)f2bf(g);
    }
    // GEMM2 partial: C(16m x 128d per wave) += gelu(H)[hf-half] @ W2 (sigma-permuted)
    #pragma unroll
    for (int n = 0; n < 8; ++n) {
      int row = n * 16 + lm;
      int sl = ((hf * 4 + q) ^ (row & 7)) * 8;
      short8 wfr = *(const short8*)&sW2[b * 8192 + row * HC + sl];
      acc2[n] = __builtin_amdgcn_mfma_f32_16x16x32_bf16(ha, wfr, acc2[n], 0, 0, 0);
    }

    __syncthreads();  // all waves done with buf b; next chunk's DMA drained
  }

  // ---- epilogue: sum hf-half partials via LDS (weights dead; reuse as fp32 scratch) ----
  float* sc = (float*)smem;   // [64][132] fp32 = 33792 B
  if (hf == 1) {
    #pragma unroll
    for (int n = 0; n < 8; ++n)
      #pragma unroll
      for (int rr = 0; rr < 4; ++rr)
        sc[(rg * 16 + q * 4 + rr) * 132 + n * 16 + lm] = acc2[n][rr];
  }
  __syncthreads();
  if (hf == 0) {
    #pragma unroll
    for (int rr = 0; rr < 4; ++rr) {
      int ml = rg * 16 + q * 4 + rr;
      int ridx = base + ml;
      if (ridx < cnt) {
        int grow = __builtin_nontemporal_load(&rows[e * NB + ridx]);
        float* op = out + (size_t)grow * DD + lm;
        #pragma unroll
        for (int n = 0; n < 8; ++n)
          __builtin_nontemporal_store(
              acc2[n][rr] + sc[(rg * 16 + q * 4 + rr) * 132 + n * 16 + lm], op + n * 16);
      }
    }
  }
}

extern "C" void kernel_launch(void* const* d_in, const int* in_sizes, int n_in,
                              void* d_out, int out_size, void* d_ws, size_t ws_size,
                              hipStream_t stream) {
  const float* x  = (const float*)d_in[0];
  const float* w1 = (const float*)d_in[1];
  const float* w2 = (const float*)d_in[2];
  const float* wg = (const float*)d_in[3];
  const float* bg = (const float*)d_in[4];
  float* out = (float*)d_out;

  // workspace: [0,64) counts ; [1024, +2MB) rows ; w1T bf16 2MB ; w2T bf16 2MB
  int* counts = (int*)d_ws;
  int* rows   = (int*)((char*)d_ws + 1024);
  unsigned short* w1T = (unsigned short*)((char*)d_ws + 1024 + (size_t)EE * NB * 4);
  unsigned short* w2T = w1T + (size_t)EE * HH * DD;

  hipMemsetAsync(d_ws, 0, 64, stream);
  hipLaunchKernelGGL(prep_kernel, dim3(1024), dim3(256), 0, stream,
                     x, wg, bg, w1, w2, counts, rows, w1T, w2T);
  hipLaunchKernelGGL(moe_gemm, dim3(EE, NB / TM), dim3(512), 0, stream,
                     x, w1T, w2T, counts, rows, out);
}